// Round 10
// baseline (6657.006 us; speedup 1.0000x reference)
//
#include <hip/hip_runtime.h>

typedef _Float16 f16;
typedef _Float16 f16x8 __attribute__((ext_vector_type(8)));
typedef float f32x4 __attribute__((ext_vector_type(4)));
typedef int iv4 __attribute__((ext_vector_type(4)));

#define BB 64
#define TT 1024
#define TP 1028
#define DD 512

// ---------------- ws layout (bytes) ----------------
static constexpr size_t SZ_XPAD = (size_t)BB * TP * DD * 2;
static constexpr size_t OFF_XA  = 0;
static constexpr size_t OFF_XB  = OFF_XA + SZ_XPAD;
static constexpr size_t OFF_KWA = OFF_XB + SZ_XPAD;
static constexpr size_t SZ_KWA  = (size_t)480 * 16384;
static constexpr size_t OFF_WKA = OFF_KWA + SZ_KWA;
static constexpr size_t SZ_WKA  = (size_t)128 * 16384;
static constexpr size_t OFF_WI8 = OFF_WKA + SZ_WKA;          // i8 W_r frags, 512KB
static constexpr size_t OFF_WQ  = OFF_WI8 + 524288;          // per-col quant step q [2048] f32
static constexpr size_t OFF_WS2 = OFF_WQ + 8192;             // per-col z scale q/16384 [2048] f32
static constexpr size_t OFF_SCSH= OFF_WS2 + 8192;            // BN scale/shift
static constexpr size_t OFF_PRE = OFF_SCSH + 16384;
static constexpr size_t SZ_PRE  = (size_t)BB * TT * 2048 * 2;

// ---------------- helpers ----------------
__device__ __forceinline__ void gld16(const void* g, void* l) {
  __builtin_amdgcn_global_load_lds(
      (const __attribute__((address_space(1))) unsigned*)g,
      (__attribute__((address_space(3))) unsigned*)l, 16, 0, 0);
}

__device__ __forceinline__ float sigm(float x) {
  x = fminf(fmaxf(x, -30.f), 30.f);
  return 1.f / (1.f + __expf(-x));
}
__device__ __forceinline__ float tanh_(float x) {
  x = fminf(fmaxf(x, -15.f), 15.f);
  float e = __expf(2.f * x);
  return (e - 1.f) / (e + 1.f);
}

// ---------------- prep kernels ----------------
__global__ void prep_scale(const float* __restrict__ cb, const float* __restrict__ gm,
                           const float* __restrict__ bt, const float* __restrict__ mn,
                           const float* __restrict__ vr, float* __restrict__ scsh) {
  int i = blockIdx.x * 256 + threadIdx.x;
  if (i < 3 * 512) {
    float rs = rsqrtf(vr[i] + 1e-3f);
    float s = gm[i] * rs;
    scsh[i] = s;
    scsh[1536 + i] = (cb[i] - mn[i]) * s + bt[i];
  }
}

__global__ void prep_x(const float* __restrict__ x, f16* __restrict__ xa, f16* __restrict__ xb) {
  size_t idx = (size_t)blockIdx.x * 256 + threadIdx.x;
  int d = (int)(idx & 511);
  int r = (int)(idx >> 9);
  int t2 = r % TP;
  int b = r / TP;
  int t = t2 - 2;
  bool in = (t >= 0 && t < TT);
  f16 v = in ? (f16)x[((size_t)b * TT + t) * DD + d] : (f16)0.f;
  xa[idx] = v;
  if (!in) xb[idx] = (f16)0.f;
}

__global__ void prep_convw(const float* __restrict__ ck, f16* __restrict__ kwa) {
  size_t idx = (size_t)blockIdx.x * 256 + threadIdx.x;
  int dout = (int)(idx & 511);
  int din = (int)((idx >> 9) & 511);
  int k5 = (int)((idx >> 18) % 5);
  int l = (int)(idx / ((size_t)5 << 18));
  f16 v = (f16)ck[idx];
  int blk = ((l * 5 + k5) * 4 + (dout >> 7)) * 8 + (din >> 6);
  int n = dout & 127, kk = din & 63;
  size_t dst = (size_t)blk * 8192 + (size_t)n * 64 + (size_t)(((kk >> 3) ^ (n & 7)) * 8) + (kk & 7);
  kwa[dst] = v;
}

__global__ void prep_wk(const float* __restrict__ wf, const float* __restrict__ wb2, f16* __restrict__ wka) {
  size_t idx = (size_t)blockIdx.x * 256 + threadIdx.x;
  int c = (int)(idx & 2047);
  int din = (int)(idx >> 11);
  float s = (c < 1024) ? wf[(size_t)din * 1024 + c] : wb2[(size_t)din * 1024 + (c - 1024)];
  int blk = (c >> 7) * 8 + (din >> 6);
  int n = c & 127, kk = din & 63;
  size_t dst = (size_t)blk * 8192 + (size_t)n * 64 + (size_t)(((kk >> 3) ^ (n & 7)) * 8) + (kk & 7);
  wka[dst] = (f16)s;
}

// per-column max -> quant step q = max/127, z-scale = q/16384
__global__ void prep_wscale(const float* __restrict__ wf, const float* __restrict__ wb2,
                            float* __restrict__ wq, float* __restrict__ ws2) {
  int i = blockIdx.x * 256 + threadIdx.x;   // 2048
  int dir = i >> 10, c = i & 1023;
  const float* src = dir ? wb2 : wf;
  float m = 1e-6f;
  for (int k = 0; k < 256; ++k) m = fmaxf(m, fabsf(src[(size_t)k * 1024 + c]));
  float q = m / 127.f;
  wq[i] = q;
  ws2[i] = q * (1.f / 16384.f);
}

// W_r -> i8 fragments: wave wav owns u[wav*32..+32), frag fi = g*2+u16, K=64 per ks
__global__ void prep_wri8(const float* __restrict__ wf, const float* __restrict__ wb2,
                          const float* __restrict__ wq, char* __restrict__ wi8) {
  size_t idx = (size_t)blockIdx.x * 256 + threadIdx.x;   // 2*256*1024
  int c = (int)(idx & 1023);
  int k = (int)((idx >> 10) & 255);
  int dir = (int)(idx >> 18);
  float s = dir ? wb2[(size_t)k * 1024 + c] : wf[(size_t)k * 1024 + c];
  float q = wq[dir * 1024 + c];
  int v = (int)rintf(s / q);
  v = v < -127 ? -127 : (v > 127 ? 127 : v);
  int g = c >> 8, u = c & 255;
  int wav = u >> 5, u16i = (u >> 4) & 1, l15 = u & 15;
  int ks = k >> 6, lhi = (k >> 4) & 3, j = k & 15;
  int fi = g * 2 + u16i;
  int lane = lhi * 16 + l15;
  size_t dst = (size_t)(dir * 8 + wav) * 32768 + (size_t)((fi * 4 + ks) * 64 + lane) * 16 + j;
  wi8[dst] = (char)v;
}

// ---------------- conv layer ----------------
__global__ __launch_bounds__(256, 3) void conv_gemm(
    const f16* __restrict__ xin, f16* __restrict__ xout,
    const f16* __restrict__ kwb, const float* __restrict__ scl, const float* __restrict__ shl) {
  __shared__ f16 Al[8192];
  __shared__ f16 Bl[8192];
  const int tid = threadIdx.x;
  const int lane = tid & 63;
  const int w = tid >> 6, wm = w >> 1, wn = w & 1;
  const int r15 = lane & 15, lhi = lane >> 4;
  const int wg = blockIdx.x;
  const int tm = wg >> 2, nb = wg & 3;
  const int b = tm >> 3, tblk = tm & 7;
  const size_t abase = (size_t)b * TP + (size_t)tblk * 128;

  int srow[4], asoff[4];
#pragma unroll
  for (int p = 0; p < 4; ++p) {
    int L = tid * 16 + p * 4096;
    int row = L >> 7, ch = (L >> 4) & 7;
    srow[p] = row;
    asoff[p] = (ch ^ (row & 7)) * 8;
  }

  f32x4 acc[4][4] = {};

  for (int k5 = 0; k5 < 5; ++k5) {
    for (int kb = 0; kb < 8; ++kb) {
#pragma unroll
      for (int p = 0; p < 4; ++p) {
        const f16* asrc = xin + (abase + (size_t)(k5 + srow[p])) * DD + kb * 64 + asoff[p];
        gld16(asrc, (char*)Al + tid * 16 + p * 4096);
      }
      const char* bbase = (const char*)kwb + (size_t)((k5 * 4 + nb) * 8 + kb) * 16384;
#pragma unroll
      for (int p = 0; p < 4; ++p)
        gld16(bbase + tid * 16 + p * 4096, (char*)Bl + tid * 16 + p * 4096);
      __syncthreads();
#pragma unroll
      for (int ks = 0; ks < 2; ++ks) {
        f16x8 af[4], bf[4];
#pragma unroll
        for (int m = 0; m < 4; ++m) {
          int row = wm * 64 + m * 16 + r15;
          int rc = (ks * 4 + lhi) ^ (row & 7);
          af[m] = *(const f16x8*)((const char*)Al + row * 128 + rc * 16);
        }
#pragma unroll
        for (int n = 0; n < 4; ++n) {
          int row = wn * 64 + n * 16 + r15;
          int rc = (ks * 4 + lhi) ^ (row & 7);
          bf[n] = *(const f16x8*)((const char*)Bl + row * 128 + rc * 16);
        }
#pragma unroll
        for (int m = 0; m < 4; ++m)
#pragma unroll
          for (int n = 0; n < 4; ++n)
            acc[m][n] = __builtin_amdgcn_mfma_f32_16x16x32_f16(af[m], bf[n], acc[m][n], 0, 0, 0);
      }
      __syncthreads();
    }
  }
#pragma unroll
  for (int n = 0; n < 4; ++n) {
    int c = nb * 128 + wn * 64 + n * 16 + r15;
    float s_ = scl[c], h_ = shl[c];
#pragma unroll
    for (int m = 0; m < 4; ++m) {
      int rl = wm * 64 + m * 16 + lhi * 4;
#pragma unroll
      for (int j = 0; j < 4; ++j) {
        float v = fmaxf(acc[m][n][j] * s_ + h_, 0.f);
        unsigned short us = __builtin_bit_cast(unsigned short, (f16)v);
        unsigned ot = (unsigned)__shfl_xor((int)us, 1, 64);
        if (!(lane & 1)) {
          unsigned pk = (unsigned)us | (ot << 16);
          *(unsigned*)((char*)xout + ((abase + 2 + rl + j) * DD + c) * 2) = pk;
        }
      }
    }
  }
}

// ---------------- LSTM input GEMM ----------------
__global__ __launch_bounds__(256, 3) void in_gemm(
    const f16* __restrict__ xin, f16* __restrict__ pre, const f16* __restrict__ wkb,
    const float* __restrict__ bfw, const float* __restrict__ bbw) {
  __shared__ f16 Al[8192];
  __shared__ f16 Bl[8192];
  const int tid = threadIdx.x;
  const int lane = tid & 63;
  const int w = tid >> 6, wm = w >> 1, wn = w & 1;
  const int r15 = lane & 15, lhi = lane >> 4;
  const int wg = blockIdx.x;
  const int tm = wg >> 4, nb = wg & 15;
  const int b = tm >> 3, tblk = tm & 7;
  const size_t abase = (size_t)b * TP + (size_t)tblk * 128 + 2;

  int srow[4], asoff[4];
#pragma unroll
  for (int p = 0; p < 4; ++p) {
    int L = tid * 16 + p * 4096;
    int row = L >> 7, ch = (L >> 4) & 7;
    srow[p] = row;
    asoff[p] = (ch ^ (row & 7)) * 8;
  }

  f32x4 acc[4][4] = {};

  for (int kb = 0; kb < 8; ++kb) {
#pragma unroll
    for (int p = 0; p < 4; ++p) {
      const f16* asrc = xin + (abase + (size_t)srow[p]) * DD + kb * 64 + asoff[p];
      gld16(asrc, (char*)Al + tid * 16 + p * 4096);
    }
    const char* bbase = (const char*)wkb + (size_t)(nb * 8 + kb) * 16384;
#pragma unroll
    for (int p = 0; p < 4; ++p)
      gld16(bbase + tid * 16 + p * 4096, (char*)Bl + tid * 16 + p * 4096);
    __syncthreads();
#pragma unroll
    for (int ks = 0; ks < 2; ++ks) {
      f16x8 af[4], bf[4];
#pragma unroll
      for (int m = 0; m < 4; ++m) {
        int row = wm * 64 + m * 16 + r15;
        int rc = (ks * 4 + lhi) ^ (row & 7);
        af[m] = *(const f16x8*)((const char*)Al + row * 128 + rc * 16);
      }
#pragma unroll
      for (int n = 0; n < 4; ++n) {
        int row = wn * 64 + n * 16 + r15;
        int rc = (ks * 4 + lhi) ^ (row & 7);
        bf[n] = *(const f16x8*)((const char*)Bl + row * 128 + rc * 16);
      }
#pragma unroll
      for (int m = 0; m < 4; ++m)
#pragma unroll
        for (int n = 0; n < 4; ++n)
          acc[m][n] = __builtin_amdgcn_mfma_f32_16x16x32_f16(af[m], bf[n], acc[m][n], 0, 0, 0);
    }
    __syncthreads();
  }
#pragma unroll
  for (int n = 0; n < 4; ++n) {
    int c = nb * 128 + wn * 64 + n * 16 + r15;
    float bias = (c < 1024) ? bfw[c] : bbw[c - 1024];
#pragma unroll
    for (int m = 0; m < 4; ++m) {
      int rl = wm * 64 + m * 16 + lhi * 4;
#pragma unroll
      for (int j = 0; j < 4; ++j) {
        float v = acc[m][n][j] + bias;
        unsigned short us = __builtin_bit_cast(unsigned short, (f16)v);
        unsigned ot = (unsigned)__shfl_xor((int)us, 1, 64);
        if (!(lane & 1)) {
          unsigned pk = (unsigned)us | (ot << 16);
          size_t prow = (size_t)b * TT + tblk * 128 + rl + j;
          *(unsigned*)((char*)pre + (prow * 2048 + c) * 2) = pk;
        }
      }
    }
  }
}

// ---------------- recurrence: fully intra-wg, i8 W + 2-plane i16 h, NO global sync ----------------
// 8 wgs = dir (wg>>2) x bblk (wg&3, 16 rows). 512 threads, 8 waves; wave w owns u[w*32..w*32+32).
// h carried as i16 = hi*256+lo (two i8 planes); z = (256*acc_hi + acc_lo) * (q_col/16384) + pre.
__global__ __launch_bounds__(512, 1) void lstm_rec(
    const char* __restrict__ wi8, const float* __restrict__ ws2,
    const f16* __restrict__ pre, float* __restrict__ out) {
  __shared__ char pldb[2][16][2088];      // [parity][row][2048 B pre-slice + pad]
  __shared__ char hbuf[2][2][16][272];    // [parity][plane hi/lo][row][256 u + pad]
  const int wg = blockIdx.x;
  const int dir = wg >> 2, bblk = wg & 3;
  const int b0 = bblk * 16;
  const int tid = threadIdx.x;
  const int w = tid >> 6, lane = tid & 63;
  const int l15 = lane & 15, lhi = lane >> 4;
  const int ubase = w * 32;

  // B fragments: 8 fi x 4 ks x v4i32 = 128 VGPRs (full K=256 resident)
  iv4 bq[8][4];
  {
    const char* wb = wi8 + (size_t)(dir * 8 + w) * 32768;
#pragma unroll
    for (int fi = 0; fi < 8; ++fi)
#pragma unroll
      for (int ks = 0; ks < 4; ++ks)
        bq[fi][ks] = *(const iv4*)(wb + (size_t)((fi * 4 + ks) * 64 + lane) * 16);
  }
  // per-lane column z-scales [u16][g]
  float sc2[2][4];
#pragma unroll
  for (int u16i = 0; u16i < 2; ++u16i)
#pragma unroll
    for (int g = 0; g < 4; ++g)
      sc2[u16i][g] = ws2[dir * 1024 + g * 256 + ubase + u16i * 16 + l15];

  for (int i = tid; i < (int)sizeof(hbuf) / 4; i += 512) ((unsigned*)hbuf)[i] = 0u;

  // stage pldb[0] for t0: wave w stages rows {2w, 2w+1}, 2 x 1KB halves each
  const int t0 = dir ? (TT - 1) : 0;
#pragma unroll
  for (int rr = 0; rr < 2; ++rr) {
    int r = w * 2 + rr;
    const f16* src = pre + ((size_t)(b0 + r) * TT + t0) * 2048 + dir * 1024 + lane * 8;
    gld16(src, &pldb[0][r][0] + lane * 16);
    gld16(src + 512, &pldb[0][r][1024] + lane * 16);
  }
  __syncthreads();

  float cst[2][4] = {};
  for (int s = 0; s < TT; ++s) {
    const int par = s & 1, npar = par ^ 1;
    const int t = dir ? (TT - 1 - s) : s;
    const int sn = (s + 1 < TT) ? (s + 1) : (TT - 1);
    const int tn = dir ? (TT - 1 - sn) : sn;

    // stage next-step pre into pldb[npar] (free: its readers finished at step s-1)
#pragma unroll
    for (int rr = 0; rr < 2; ++rr) {
      int r = w * 2 + rr;
      const f16* src = pre + ((size_t)(b0 + r) * TT + tn) * 2048 + dir * 1024 + lane * 8;
      gld16(src, &pldb[npar][r][0] + lane * 16);
      gld16(src + 512, &pldb[npar][r][1024] + lane * 16);
    }

    // MFMA: full K=256, two planes, ks-interleaved (a-frags transient)
    iv4 acch[8], accl[8];
#pragma unroll
    for (int ks = 0; ks < 4; ++ks) {
      iv4 ahi = *(const iv4*)(&hbuf[par][0][l15][ks * 64 + lhi * 16]);
      iv4 alo = *(const iv4*)(&hbuf[par][1][l15][ks * 64 + lhi * 16]);
      if (ks == 0) {
#pragma unroll
        for (int fi = 0; fi < 8; ++fi) {
          acch[fi] = __builtin_amdgcn_mfma_i32_16x16x64_i8(ahi, bq[fi][0], (iv4){0, 0, 0, 0}, 0, 0, 0);
          accl[fi] = __builtin_amdgcn_mfma_i32_16x16x64_i8(alo, bq[fi][0], (iv4){0, 0, 0, 0}, 0, 0, 0);
        }
      } else {
#pragma unroll
        for (int fi = 0; fi < 8; ++fi) {
          acch[fi] = __builtin_amdgcn_mfma_i32_16x16x64_i8(ahi, bq[fi][ks], acch[fi], 0, 0, 0);
          accl[fi] = __builtin_amdgcn_mfma_i32_16x16x64_i8(alo, bq[fi][ks], accl[fi], 0, 0, 0);
        }
      }
    }

    // gates: 8 h per lane (2 u16-blocks x 4 rows)
#pragma unroll
    for (int u16i = 0; u16i < 2; ++u16i) {
      const int u = ubase + u16i * 16 + l15;
#pragma unroll
      for (int j = 0; j < 4; ++j) {
        const int row = lhi * 4 + j;
        float z[4];
#pragma unroll
        for (int g = 0; g < 4; ++g) {
          int zi = acch[g * 2 + u16i][j] * 256 + accl[g * 2 + u16i][j];
          f16 pv = *(const f16*)(&pldb[par][row][g * 512 + u * 2]);
          z[g] = (float)zi * sc2[u16i][g] + (float)pv;
        }
        float ig = sigm(z[0]), fg = sigm(z[1]), gg = tanh_(z[2]), og = sigm(z[3]);
        float cc = fg * cst[u16i][j] + ig * gg;
        cst[u16i][j] = cc;
        float hv = og * tanh_(cc);
        int h16 = (int)rintf(hv * 16384.f);
        int hi = (h16 + 128) >> 8;
        int lo = h16 - (hi << 8);
        hbuf[npar][0][row][u] = (char)hi;
        hbuf[npar][1][row][u] = (char)lo;
        out[((size_t)(b0 + row) * TT + t) * DD + dir * 256 + u] = hv;
      }
    }
    __syncthreads();   // h(npar) + pldb(npar) staged (compiler drains vmcnt before barrier)
  }
}

// ---------------- launch ----------------
extern "C" void kernel_launch(void* const* d_in, const int* in_sizes, int n_in,
                              void* d_out, int out_size, void* d_ws, size_t ws_size,
                              hipStream_t stream) {
  (void)in_sizes; (void)n_in; (void)out_size; (void)ws_size;
  char* ws = (char*)d_ws;
  f16* xa   = (f16*)(ws + OFF_XA);
  f16* xb   = (f16*)(ws + OFF_XB);
  f16* kwa  = (f16*)(ws + OFF_KWA);
  f16* wka  = (f16*)(ws + OFF_WKA);
  char* wi8 = ws + OFF_WI8;
  float* wq  = (float*)(ws + OFF_WQ);
  float* ws2 = (float*)(ws + OFF_WS2);
  float* scsh = (float*)(ws + OFF_SCSH);
  f16* pre  = (f16*)(ws + OFF_PRE);

  const float* x   = (const float*)d_in[0];
  const float* ck  = (const float*)d_in[1];
  const float* cb  = (const float*)d_in[2];
  const float* gm  = (const float*)d_in[3];
  const float* bt  = (const float*)d_in[4];
  const float* mn  = (const float*)d_in[5];
  const float* vr  = (const float*)d_in[6];
  const float* wkf = (const float*)d_in[7];
  const float* wrf = (const float*)d_in[8];
  const float* bf  = (const float*)d_in[9];
  const float* wkb = (const float*)d_in[10];
  const float* wrb = (const float*)d_in[11];
  const float* bb2 = (const float*)d_in[12];

  prep_scale<<<6, 256, 0, stream>>>(cb, gm, bt, mn, vr, scsh);
  prep_x<<<(BB * TP * DD) / 256, 256, 0, stream>>>(x, xa, xb);
  prep_convw<<<(3 * 5 * 512 * 512) / 256, 256, 0, stream>>>(ck, kwa);
  prep_wk<<<(512 * 2048) / 256, 256, 0, stream>>>(wkf, wkb, wka);
  prep_wscale<<<8, 256, 0, stream>>>(wrf, wrb, wq, ws2);
  prep_wri8<<<(2 * 256 * 1024) / 256, 256, 0, stream>>>(wrf, wrb, wq, wi8);

  conv_gemm<<<2048, 256, 0, stream>>>(xa, xb, kwa,                  scsh,          scsh + 1536);
  conv_gemm<<<2048, 256, 0, stream>>>(xb, xa, kwa + 1 * 160 * 8192, scsh + 512,   scsh + 1536 + 512);
  conv_gemm<<<2048, 256, 0, stream>>>(xa, xb, kwa + 2 * 160 * 8192, scsh + 1024,  scsh + 1536 + 1024);

  in_gemm<<<8192, 256, 0, stream>>>(xb, pre, wka, bf, bb2);

  lstm_rec<<<8, 512, 0, stream>>>(wi8, ws2, pre, (float*)d_out);
}

// Round 11
// 6001.543 us; speedup vs baseline: 1.1092x; 1.1092x over previous
//
#include <hip/hip_runtime.h>

typedef _Float16 f16;
typedef _Float16 f16x8 __attribute__((ext_vector_type(8)));
typedef float f32x4 __attribute__((ext_vector_type(4)));
typedef int iv4 __attribute__((ext_vector_type(4)));

#define BB 64
#define TT 1024
#define TP 1028
#define DD 512

// ---------------- ws layout (bytes) ----------------
static constexpr size_t SZ_XPAD = (size_t)BB * TP * DD * 2;
static constexpr size_t OFF_XA  = 0;
static constexpr size_t OFF_XB  = OFF_XA + SZ_XPAD;
static constexpr size_t OFF_KWA = OFF_XB + SZ_XPAD;
static constexpr size_t SZ_KWA  = (size_t)480 * 16384;
static constexpr size_t OFF_WKA = OFF_KWA + SZ_KWA;
static constexpr size_t SZ_WKA  = (size_t)128 * 16384;
static constexpr size_t OFF_WI8 = OFF_WKA + SZ_WKA;          // i8 W_r frags, 512KB
static constexpr size_t OFF_WQ  = OFF_WI8 + 524288;          // per-col quant step q [2048] f32
static constexpr size_t OFF_WS2 = OFF_WQ + 8192;             // per-col z scale q/16384 [2048] f32
static constexpr size_t OFF_SCSH= OFF_WS2 + 8192;            // BN scale/shift
static constexpr size_t OFF_PRE = OFF_SCSH + 16384;
static constexpr size_t SZ_PRE  = (size_t)BB * TT * 2048 * 2;

// ---------------- helpers ----------------
__device__ __forceinline__ void gld16(const void* g, void* l) {
  __builtin_amdgcn_global_load_lds(
      (const __attribute__((address_space(1))) unsigned*)g,
      (__attribute__((address_space(3))) unsigned*)l, 16, 0, 0);
}

// rcp-based gates: no IEEE division sequences (v_div_scale/fmas/fixup)
__device__ __forceinline__ float sigm(float x) {
  // x -> -inf: exp(-x)=inf -> rcp(inf)=0 (correct); x -> +inf: exp->0 -> 1 (correct)
  return __builtin_amdgcn_rcpf(1.f + __expf(-x));
}
__device__ __forceinline__ float tanh_(float x) {
  float e = __expf(2.f * fminf(x, 15.f));   // lower side: e->0 gives -1 exactly
  return (e - 1.f) * __builtin_amdgcn_rcpf(e + 1.f);
}

// ---------------- prep kernels ----------------
__global__ void prep_scale(const float* __restrict__ cb, const float* __restrict__ gm,
                           const float* __restrict__ bt, const float* __restrict__ mn,
                           const float* __restrict__ vr, float* __restrict__ scsh) {
  int i = blockIdx.x * 256 + threadIdx.x;
  if (i < 3 * 512) {
    float rs = rsqrtf(vr[i] + 1e-3f);
    float s = gm[i] * rs;
    scsh[i] = s;
    scsh[1536 + i] = (cb[i] - mn[i]) * s + bt[i];
  }
}

__global__ void prep_x(const float* __restrict__ x, f16* __restrict__ xa, f16* __restrict__ xb) {
  size_t idx = (size_t)blockIdx.x * 256 + threadIdx.x;
  int d = (int)(idx & 511);
  int r = (int)(idx >> 9);
  int t2 = r % TP;
  int b = r / TP;
  int t = t2 - 2;
  bool in = (t >= 0 && t < TT);
  f16 v = in ? (f16)x[((size_t)b * TT + t) * DD + d] : (f16)0.f;
  xa[idx] = v;
  if (!in) xb[idx] = (f16)0.f;
}

__global__ void prep_convw(const float* __restrict__ ck, f16* __restrict__ kwa) {
  size_t idx = (size_t)blockIdx.x * 256 + threadIdx.x;
  int dout = (int)(idx & 511);
  int din = (int)((idx >> 9) & 511);
  int k5 = (int)((idx >> 18) % 5);
  int l = (int)(idx / ((size_t)5 << 18));
  f16 v = (f16)ck[idx];
  int blk = ((l * 5 + k5) * 4 + (dout >> 7)) * 8 + (din >> 6);
  int n = dout & 127, kk = din & 63;
  size_t dst = (size_t)blk * 8192 + (size_t)n * 64 + (size_t)(((kk >> 3) ^ (n & 7)) * 8) + (kk & 7);
  kwa[dst] = v;
}

__global__ void prep_wk(const float* __restrict__ wf, const float* __restrict__ wb2, f16* __restrict__ wka) {
  size_t idx = (size_t)blockIdx.x * 256 + threadIdx.x;
  int c = (int)(idx & 2047);
  int din = (int)(idx >> 11);
  float s = (c < 1024) ? wf[(size_t)din * 1024 + c] : wb2[(size_t)din * 1024 + (c - 1024)];
  int blk = (c >> 7) * 8 + (din >> 6);
  int n = c & 127, kk = din & 63;
  size_t dst = (size_t)blk * 8192 + (size_t)n * 64 + (size_t)(((kk >> 3) ^ (n & 7)) * 8) + (kk & 7);
  wka[dst] = (f16)s;
}

// per-column max -> quant step q = max/127, z-scale = q/16384
__global__ void prep_wscale(const float* __restrict__ wf, const float* __restrict__ wb2,
                            float* __restrict__ wq, float* __restrict__ ws2) {
  int i = blockIdx.x * 256 + threadIdx.x;   // 2048
  int dir = i >> 10, c = i & 1023;
  const float* src = dir ? wb2 : wf;
  float m = 1e-6f;
  for (int k = 0; k < 256; ++k) m = fmaxf(m, fabsf(src[(size_t)k * 1024 + c]));
  float q = m / 127.f;
  wq[i] = q;
  ws2[i] = q * (1.f / 16384.f);
}

// W_r -> i8 fragments: wave wav owns u[wav*32..+32), frag fi = g*2+u16, K=64 per ks
__global__ void prep_wri8(const float* __restrict__ wf, const float* __restrict__ wb2,
                          const float* __restrict__ wq, char* __restrict__ wi8) {
  size_t idx = (size_t)blockIdx.x * 256 + threadIdx.x;   // 2*256*1024
  int c = (int)(idx & 1023);
  int k = (int)((idx >> 10) & 255);
  int dir = (int)(idx >> 18);
  float s = dir ? wb2[(size_t)k * 1024 + c] : wf[(size_t)k * 1024 + c];
  float q = wq[dir * 1024 + c];
  int v = (int)rintf(s / q);
  v = v < -127 ? -127 : (v > 127 ? 127 : v);
  int g = c >> 8, u = c & 255;
  int wav = u >> 5, u16i = (u >> 4) & 1, l15 = u & 15;
  int ks = k >> 6, lhi = (k >> 4) & 3, j = k & 15;
  int fi = g * 2 + u16i;
  int lane = lhi * 16 + l15;
  size_t dst = (size_t)(dir * 8 + wav) * 32768 + (size_t)((fi * 4 + ks) * 64 + lane) * 16 + j;
  wi8[dst] = (char)v;
}

// ---------------- conv layer ----------------
__global__ __launch_bounds__(256, 3) void conv_gemm(
    const f16* __restrict__ xin, f16* __restrict__ xout,
    const f16* __restrict__ kwb, const float* __restrict__ scl, const float* __restrict__ shl) {
  __shared__ f16 Al[8192];
  __shared__ f16 Bl[8192];
  const int tid = threadIdx.x;
  const int lane = tid & 63;
  const int w = tid >> 6, wm = w >> 1, wn = w & 1;
  const int r15 = lane & 15, lhi = lane >> 4;
  const int wg = blockIdx.x;
  const int tm = wg >> 2, nb = wg & 3;
  const int b = tm >> 3, tblk = tm & 7;
  const size_t abase = (size_t)b * TP + (size_t)tblk * 128;

  int srow[4], asoff[4];
#pragma unroll
  for (int p = 0; p < 4; ++p) {
    int L = tid * 16 + p * 4096;
    int row = L >> 7, ch = (L >> 4) & 7;
    srow[p] = row;
    asoff[p] = (ch ^ (row & 7)) * 8;
  }

  f32x4 acc[4][4] = {};

  for (int k5 = 0; k5 < 5; ++k5) {
    for (int kb = 0; kb < 8; ++kb) {
#pragma unroll
      for (int p = 0; p < 4; ++p) {
        const f16* asrc = xin + (abase + (size_t)(k5 + srow[p])) * DD + kb * 64 + asoff[p];
        gld16(asrc, (char*)Al + tid * 16 + p * 4096);
      }
      const char* bbase = (const char*)kwb + (size_t)((k5 * 4 + nb) * 8 + kb) * 16384;
#pragma unroll
      for (int p = 0; p < 4; ++p)
        gld16(bbase + tid * 16 + p * 4096, (char*)Bl + tid * 16 + p * 4096);
      __syncthreads();
#pragma unroll
      for (int ks = 0; ks < 2; ++ks) {
        f16x8 af[4], bf[4];
#pragma unroll
        for (int m = 0; m < 4; ++m) {
          int row = wm * 64 + m * 16 + r15;
          int rc = (ks * 4 + lhi) ^ (row & 7);
          af[m] = *(const f16x8*)((const char*)Al + row * 128 + rc * 16);
        }
#pragma unroll
        for (int n = 0; n < 4; ++n) {
          int row = wn * 64 + n * 16 + r15;
          int rc = (ks * 4 + lhi) ^ (row & 7);
          bf[n] = *(const f16x8*)((const char*)Bl + row * 128 + rc * 16);
        }
#pragma unroll
        for (int m = 0; m < 4; ++m)
#pragma unroll
          for (int n = 0; n < 4; ++n)
            acc[m][n] = __builtin_amdgcn_mfma_f32_16x16x32_f16(af[m], bf[n], acc[m][n], 0, 0, 0);
      }
      __syncthreads();
    }
  }
#pragma unroll
  for (int n = 0; n < 4; ++n) {
    int c = nb * 128 + wn * 64 + n * 16 + r15;
    float s_ = scl[c], h_ = shl[c];
#pragma unroll
    for (int m = 0; m < 4; ++m) {
      int rl = wm * 64 + m * 16 + lhi * 4;
#pragma unroll
      for (int j = 0; j < 4; ++j) {
        float v = fmaxf(acc[m][n][j] * s_ + h_, 0.f);
        unsigned short us = __builtin_bit_cast(unsigned short, (f16)v);
        unsigned ot = (unsigned)__shfl_xor((int)us, 1, 64);
        if (!(lane & 1)) {
          unsigned pk = (unsigned)us | (ot << 16);
          *(unsigned*)((char*)xout + ((abase + 2 + rl + j) * DD + c) * 2) = pk;
        }
      }
    }
  }
}

// ---------------- LSTM input GEMM ----------------
__global__ __launch_bounds__(256, 3) void in_gemm(
    const f16* __restrict__ xin, f16* __restrict__ pre, const f16* __restrict__ wkb,
    const float* __restrict__ bfw, const float* __restrict__ bbw) {
  __shared__ f16 Al[8192];
  __shared__ f16 Bl[8192];
  const int tid = threadIdx.x;
  const int lane = tid & 63;
  const int w = tid >> 6, wm = w >> 1, wn = w & 1;
  const int r15 = lane & 15, lhi = lane >> 4;
  const int wg = blockIdx.x;
  const int tm = wg >> 4, nb = wg & 15;
  const int b = tm >> 3, tblk = tm & 7;
  const size_t abase = (size_t)b * TP + (size_t)tblk * 128 + 2;

  int srow[4], asoff[4];
#pragma unroll
  for (int p = 0; p < 4; ++p) {
    int L = tid * 16 + p * 4096;
    int row = L >> 7, ch = (L >> 4) & 7;
    srow[p] = row;
    asoff[p] = (ch ^ (row & 7)) * 8;
  }

  f32x4 acc[4][4] = {};

  for (int kb = 0; kb < 8; ++kb) {
#pragma unroll
    for (int p = 0; p < 4; ++p) {
      const f16* asrc = xin + (abase + (size_t)srow[p]) * DD + kb * 64 + asoff[p];
      gld16(asrc, (char*)Al + tid * 16 + p * 4096);
    }
    const char* bbase = (const char*)wkb + (size_t)(nb * 8 + kb) * 16384;
#pragma unroll
    for (int p = 0; p < 4; ++p)
      gld16(bbase + tid * 16 + p * 4096, (char*)Bl + tid * 16 + p * 4096);
    __syncthreads();
#pragma unroll
    for (int ks = 0; ks < 2; ++ks) {
      f16x8 af[4], bf[4];
#pragma unroll
      for (int m = 0; m < 4; ++m) {
        int row = wm * 64 + m * 16 + r15;
        int rc = (ks * 4 + lhi) ^ (row & 7);
        af[m] = *(const f16x8*)((const char*)Al + row * 128 + rc * 16);
      }
#pragma unroll
      for (int n = 0; n < 4; ++n) {
        int row = wn * 64 + n * 16 + r15;
        int rc = (ks * 4 + lhi) ^ (row & 7);
        bf[n] = *(const f16x8*)((const char*)Bl + row * 128 + rc * 16);
      }
#pragma unroll
      for (int m = 0; m < 4; ++m)
#pragma unroll
        for (int n = 0; n < 4; ++n)
          acc[m][n] = __builtin_amdgcn_mfma_f32_16x16x32_f16(af[m], bf[n], acc[m][n], 0, 0, 0);
    }
    __syncthreads();
  }
#pragma unroll
  for (int n = 0; n < 4; ++n) {
    int c = nb * 128 + wn * 64 + n * 16 + r15;
    float bias = (c < 1024) ? bfw[c] : bbw[c - 1024];
#pragma unroll
    for (int m = 0; m < 4; ++m) {
      int rl = wm * 64 + m * 16 + lhi * 4;
#pragma unroll
      for (int j = 0; j < 4; ++j) {
        float v = acc[m][n][j] + bias;
        unsigned short us = __builtin_bit_cast(unsigned short, (f16)v);
        unsigned ot = (unsigned)__shfl_xor((int)us, 1, 64);
        if (!(lane & 1)) {
          unsigned pk = (unsigned)us | (ot << 16);
          size_t prow = (size_t)b * TT + tblk * 128 + rl + j;
          *(unsigned*)((char*)pre + (prow * 2048 + c) * 2) = pk;
        }
      }
    }
  }
}

// ---------------- recurrence: intra-wg i8, reg-resident pre, rcp gates ----------------
// 8 wgs = dir (wg>>2) x bblk (wg&3, 16 rows). 8 waves; wave w owns u[w*32..w*32+32).
// h carried as i16 = hi*256+lo (two i8 planes); z = (256*acc_hi + acc_lo)*(q/16384) + pre.
__global__ __launch_bounds__(512, 1) void lstm_rec(
    const char* __restrict__ wi8, const float* __restrict__ ws2,
    const f16* __restrict__ pre, float* __restrict__ out) {
  __shared__ char hbuf[2][2][16][272];    // [parity][plane hi/lo][row][256 u + pad]
  const int wg = blockIdx.x;
  const int dir = wg >> 2, bblk = wg & 3;
  const int b0 = bblk * 16;
  const int tid = threadIdx.x;
  const int w = tid >> 6, lane = tid & 63;
  const int l15 = lane & 15, lhi = lane >> 4;
  const int ubase = w * 32;

  // B fragments: 8 fi x 4 ks x v4i32 = 128 regs (full K=256 resident)
  iv4 bq[8][4];
  {
    const char* wb = wi8 + (size_t)(dir * 8 + w) * 32768;
#pragma unroll
    for (int fi = 0; fi < 8; ++fi)
#pragma unroll
      for (int ks = 0; ks < 4; ++ks)
        bq[fi][ks] = *(const iv4*)(wb + (size_t)((fi * 4 + ks) * 64 + lane) * 16);
  }
  // per-lane column z-scales [u16][g]
  float sc2[2][4];
#pragma unroll
  for (int u16i = 0; u16i < 2; ++u16i)
#pragma unroll
    for (int g = 0; g < 4; ++g)
      sc2[u16i][g] = ws2[dir * 1024 + g * 256 + ubase + u16i * 16 + l15];

  for (int i = tid; i < (int)sizeof(hbuf) / 4; i += 512) ((unsigned*)hbuf)[i] = 0u;

  // pre -> registers, double-buffered across steps (statically indexed arrays)
  const unsigned short* pr16 = (const unsigned short*)pre;
  unsigned short pC[2][4][4], pN[2][4][4];
  const int t0 = dir ? (TT - 1) : 0;
#pragma unroll
  for (int u16i = 0; u16i < 2; ++u16i)
#pragma unroll
    for (int g = 0; g < 4; ++g)
#pragma unroll
      for (int j = 0; j < 4; ++j)
        pC[u16i][g][j] = pr16[((size_t)(b0 + lhi * 4 + j) * TT + t0) * 2048
                              + dir * 1024 + g * 256 + ubase + u16i * 16 + l15];
  __syncthreads();

  float cst[2][4] = {};
  for (int s = 0; s < TT; ++s) {
    const int par = s & 1, npar = par ^ 1;
    const int t = dir ? (TT - 1 - s) : s;
    const int sn = (s + 1 < TT) ? (s + 1) : (TT - 1);
    const int tn = dir ? (TT - 1 - sn) : sn;

    // prefetch next-step pre into regs (hidden under MFMA + gates)
#pragma unroll
    for (int u16i = 0; u16i < 2; ++u16i)
#pragma unroll
      for (int g = 0; g < 4; ++g)
#pragma unroll
        for (int j = 0; j < 4; ++j)
          pN[u16i][g][j] = pr16[((size_t)(b0 + lhi * 4 + j) * TT + tn) * 2048
                                + dir * 1024 + g * 256 + ubase + u16i * 16 + l15];

    // MFMA: full K=256, two planes, ks-interleaved
    iv4 acch[8], accl[8];
#pragma unroll
    for (int ks = 0; ks < 4; ++ks) {
      iv4 ahi = *(const iv4*)(&hbuf[par][0][l15][ks * 64 + lhi * 16]);
      iv4 alo = *(const iv4*)(&hbuf[par][1][l15][ks * 64 + lhi * 16]);
      if (ks == 0) {
#pragma unroll
        for (int fi = 0; fi < 8; ++fi) {
          acch[fi] = __builtin_amdgcn_mfma_i32_16x16x64_i8(ahi, bq[fi][0], (iv4){0, 0, 0, 0}, 0, 0, 0);
          accl[fi] = __builtin_amdgcn_mfma_i32_16x16x64_i8(alo, bq[fi][0], (iv4){0, 0, 0, 0}, 0, 0, 0);
        }
      } else {
#pragma unroll
        for (int fi = 0; fi < 8; ++fi) {
          acch[fi] = __builtin_amdgcn_mfma_i32_16x16x64_i8(ahi, bq[fi][ks], acch[fi], 0, 0, 0);
          accl[fi] = __builtin_amdgcn_mfma_i32_16x16x64_i8(alo, bq[fi][ks], accl[fi], 0, 0, 0);
        }
      }
    }

    // gates: 8 h per lane (2 u16-blocks x 4 rows), all-rcp transcendentals
#pragma unroll
    for (int u16i = 0; u16i < 2; ++u16i) {
      const int u = ubase + u16i * 16 + l15;
#pragma unroll
      for (int j = 0; j < 4; ++j) {
        const int row = lhi * 4 + j;
        float z[4];
#pragma unroll
        for (int g = 0; g < 4; ++g) {
          int zi = (acch[g * 2 + u16i][j] << 8) + accl[g * 2 + u16i][j];
          z[g] = (float)zi * sc2[u16i][g]
               + (float)__builtin_bit_cast(f16, pC[u16i][g][j]);
        }
        float ig = sigm(z[0]), fg = sigm(z[1]), gg = tanh_(z[2]), og = sigm(z[3]);
        float cc = fg * cst[u16i][j] + ig * gg;
        cst[u16i][j] = cc;
        float hv = og * tanh_(cc);
        int h16 = (int)rintf(hv * 16384.f);
        int hi = (h16 + 128) >> 8;
        int lo = h16 - (hi << 8);
        hbuf[npar][0][row][u] = (char)hi;
        hbuf[npar][1][row][u] = (char)lo;
        out[((size_t)(b0 + row) * TT + t) * DD + dir * 256 + u] = hv;
      }
    }

    // rotate pre buffers (cheap reg moves; forces wait on pN well after issue)
#pragma unroll
    for (int u16i = 0; u16i < 2; ++u16i)
#pragma unroll
      for (int g = 0; g < 4; ++g)
#pragma unroll
        for (int j = 0; j < 4; ++j)
          pC[u16i][g][j] = pN[u16i][g][j];

    __syncthreads();   // h(npar) visible to all waves
  }
}

// ---------------- launch ----------------
extern "C" void kernel_launch(void* const* d_in, const int* in_sizes, int n_in,
                              void* d_out, int out_size, void* d_ws, size_t ws_size,
                              hipStream_t stream) {
  (void)in_sizes; (void)n_in; (void)out_size; (void)ws_size;
  char* ws = (char*)d_ws;
  f16* xa   = (f16*)(ws + OFF_XA);
  f16* xb   = (f16*)(ws + OFF_XB);
  f16* kwa  = (f16*)(ws + OFF_KWA);
  f16* wka  = (f16*)(ws + OFF_WKA);
  char* wi8 = ws + OFF_WI8;
  float* wq  = (float*)(ws + OFF_WQ);
  float* ws2 = (float*)(ws + OFF_WS2);
  float* scsh = (float*)(ws + OFF_SCSH);
  f16* pre  = (f16*)(ws + OFF_PRE);

  const float* x   = (const float*)d_in[0];
  const float* ck  = (const float*)d_in[1];
  const float* cb  = (const float*)d_in[2];
  const float* gm  = (const float*)d_in[3];
  const float* bt  = (const float*)d_in[4];
  const float* mn  = (const float*)d_in[5];
  const float* vr  = (const float*)d_in[6];
  const float* wkf = (const float*)d_in[7];
  const float* wrf = (const float*)d_in[8];
  const float* bf  = (const float*)d_in[9];
  const float* wkb = (const float*)d_in[10];
  const float* wrb = (const float*)d_in[11];
  const float* bb2 = (const float*)d_in[12];

  prep_scale<<<6, 256, 0, stream>>>(cb, gm, bt, mn, vr, scsh);
  prep_x<<<(BB * TP * DD) / 256, 256, 0, stream>>>(x, xa, xb);
  prep_convw<<<(3 * 5 * 512 * 512) / 256, 256, 0, stream>>>(ck, kwa);
  prep_wk<<<(512 * 2048) / 256, 256, 0, stream>>>(wkf, wkb, wka);
  prep_wscale<<<8, 256, 0, stream>>>(wrf, wrb, wq, ws2);
  prep_wri8<<<(2 * 256 * 1024) / 256, 256, 0, stream>>>(wrf, wrb, wq, wi8);

  conv_gemm<<<2048, 256, 0, stream>>>(xa, xb, kwa,                  scsh,          scsh + 1536);
  conv_gemm<<<2048, 256, 0, stream>>>(xb, xa, kwa + 1 * 160 * 8192, scsh + 512,   scsh + 1536 + 512);
  conv_gemm<<<2048, 256, 0, stream>>>(xa, xb, kwa + 2 * 160 * 8192, scsh + 1024,  scsh + 1536 + 1024);

  in_gemm<<<8192, 256, 0, stream>>>(xb, pre, wka, bf, bb2);

  lstm_rec<<<8, 512, 0, stream>>>(wi8, ws2, pre, (float*)d_out);
}